// Round 1
// baseline (1231.367 us; speedup 1.0000x reference)
//
#include <hip/hip_runtime.h>
#include <hip/hip_bf16.h>

// WindowAttention: x[2048,49,256] -> out[2048,49,256], fp32.
// DIM=256, H=8, hd=32, N=49, windows=64, scale=32^-0.5.
#define NTOK 49
#define NHEAD 8
#define HDIM 32
#define DIMC 256
#define SCALE_F 0.17677669529663687f

constexpr int K_DIM = 256;

// ---------------- bias expand: [169,8] gathered via rel_index -> [8,49,49] -----
__global__ __launch_bounds__(256) void bias_expand_kernel(
    const float* __restrict__ bias_table,   // [169,8]
    const int*   __restrict__ rel_index,    // [49*49]
    float* __restrict__ biasf)              // [8,49,49]
{
    int idx = blockIdx.x * 256 + threadIdx.x;
    if (idx >= NHEAD * NTOK * NTOK) return;
    int h  = idx / (NTOK * NTOK);
    int ij = idx - h * (NTOK * NTOK);
    biasf[idx] = bias_table[rel_index[ij] * NHEAD + h];
}

// ---------------- generic fp32 GEMM: Y[M,N] = X[M,256] @ W[256,N] + Bv --------
// 128x128 tile, 256 threads, 8x8 register tile per thread, K-tile 16.
__global__ __launch_bounds__(256) void gemm_bias_kernel(
    const float* __restrict__ X,   // [M, 256]
    const float* __restrict__ W,   // [256, N]
    const float* __restrict__ Bv,  // [N]
    float* __restrict__ Y,         // [M, N]
    int M, int N)
{
    __shared__ float As[16][136];  // [k][m], padded
    __shared__ float Bs[16][136];  // [k][n], padded

    const int tid = threadIdx.x;
    const int m0 = blockIdx.y * 128;
    const int n0 = blockIdx.x * 128;
    const int ty = tid >> 4;        // 0..15 -> rows ty*8..+7
    const int tx = tid & 15;        // 0..15 -> cols tx*8..+7

    // load assignments
    const int ar = tid >> 1;             // 0..127
    const int ak = (tid & 1) * 8;        // 0 or 8
    const int bk = tid >> 4;             // 0..15
    const int bn = (tid & 15) * 8;       // 0..120

    float acc[8][8];
    #pragma unroll
    for (int i = 0; i < 8; ++i)
        #pragma unroll
        for (int j = 0; j < 8; ++j) acc[i][j] = 0.f;

    for (int k0 = 0; k0 < K_DIM; k0 += 16) {
        int am = m0 + ar; if (am >= M) am = M - 1;   // clamp (reads stay in-bounds)
        const float4* ap = (const float4*)(X + (size_t)am * K_DIM + k0 + ak);
        float4 a0 = ap[0], a1 = ap[1];
        const float4* bp = (const float4*)(W + (size_t)(k0 + bk) * N + n0 + bn);
        float4 b0 = bp[0], b1 = bp[1];

        __syncthreads();
        As[ak+0][ar] = a0.x; As[ak+1][ar] = a0.y; As[ak+2][ar] = a0.z; As[ak+3][ar] = a0.w;
        As[ak+4][ar] = a1.x; As[ak+5][ar] = a1.y; As[ak+6][ar] = a1.z; As[ak+7][ar] = a1.w;
        *(float4*)&Bs[bk][bn]     = b0;
        *(float4*)&Bs[bk][bn + 4] = b1;
        __syncthreads();

        #pragma unroll
        for (int kk = 0; kk < 16; ++kk) {
            float4 a0v = *(const float4*)&As[kk][ty * 8];
            float4 a1v = *(const float4*)&As[kk][ty * 8 + 4];
            float4 b0v = *(const float4*)&Bs[kk][tx * 8];
            float4 b1v = *(const float4*)&Bs[kk][tx * 8 + 4];
            float av[8] = {a0v.x, a0v.y, a0v.z, a0v.w, a1v.x, a1v.y, a1v.z, a1v.w};
            float bv[8] = {b0v.x, b0v.y, b0v.z, b0v.w, b1v.x, b1v.y, b1v.z, b1v.w};
            #pragma unroll
            for (int i = 0; i < 8; ++i)
                #pragma unroll
                for (int j = 0; j < 8; ++j)
                    acc[i][j] += av[i] * bv[j];
        }
    }

    const float4 bv0 = *(const float4*)(Bv + n0 + tx * 8);
    const float4 bv1 = *(const float4*)(Bv + n0 + tx * 8 + 4);
    #pragma unroll
    for (int i = 0; i < 8; ++i) {
        int m = m0 + ty * 8 + i;
        if (m < M) {
            float4 o0, o1;
            o0.x = acc[i][0] + bv0.x; o0.y = acc[i][1] + bv0.y;
            o0.z = acc[i][2] + bv0.z; o0.w = acc[i][3] + bv0.w;
            o1.x = acc[i][4] + bv1.x; o1.y = acc[i][5] + bv1.y;
            o1.z = acc[i][6] + bv1.z; o1.w = acc[i][7] + bv1.w;
            float4* yp = (float4*)(Y + (size_t)m * N + n0 + tx * 8);
            yp[0] = o0; yp[1] = o1;
        }
    }
}

// ---------------- attention: per-window scores+softmax+PV ---------------------
// qkv chunk layout: [wc*49, 768] with col = s*256 + h*32 + d.
// out1 layout: [wc*49, 256] with col = h*32 + d.
__global__ __launch_bounds__(256) void attn_kernel(
    const float* __restrict__ qkv,
    const float* __restrict__ mask,    // [64,49,49]
    const float* __restrict__ biasf,   // [8,49,49]
    float* __restrict__ out1,
    int win0)
{
    __shared__ float qs[NTOK][36];
    __shared__ float ks[NTOK][37];   // pad 37 (odd stride) -> conflict-free j-strided reads
    __shared__ float vs[NTOK][36];
    __shared__ float sc[NTOK][52];

    const int tid = threadIdx.x;
    const int b = blockIdx.x;                 // local window index
    const int w = (win0 + b) & 63;            // mask window index
    const float* base = qkv + (size_t)b * NTOK * 768;
    const float* mk = mask + (size_t)w * (NTOK * NTOK);

    for (int h = 0; h < NHEAD; ++h) {
        __syncthreads();   // protect previous iteration's LDS reads
        // ---- load q,k,v for this head (float4 per row-chunk) ----
        for (int idx = tid; idx < NTOK * 8; idx += 256) {
            int i = idx >> 3;
            int d4 = (idx & 7) * 4;
            const float* rp = base + (size_t)i * 768 + h * HDIM + d4;
            float4 qv = *(const float4*)(rp);
            float4 kv = *(const float4*)(rp + 256);
            float4 vv = *(const float4*)(rp + 512);
            *(float4*)&qs[i][d4] = qv;
            ks[i][d4 + 0] = kv.x; ks[i][d4 + 1] = kv.y;
            ks[i][d4 + 2] = kv.z; ks[i][d4 + 3] = kv.w;
            *(float4*)&vs[i][d4] = vv;
        }
        __syncthreads();
        // ---- scores: s[i][j] = scale * q_i . k_j + bias[h,i,j] + mask[w,i,j] ----
        for (int idx = tid; idx < NTOK * NTOK; idx += 256) {
            int i = idx / NTOK;
            int j = idx - i * NTOK;
            float dot = 0.f;
            #pragma unroll
            for (int d = 0; d < HDIM; ++d) dot += qs[i][d] * ks[j][d];
            sc[i][j] = dot * SCALE_F + biasf[h * (NTOK * NTOK) + idx] + mk[idx];
        }
        __syncthreads();
        // ---- softmax over j, one thread per row ----
        if (tid < NTOK) {
            int i = tid;
            float m = -1e30f;
            for (int j = 0; j < NTOK; ++j) m = fmaxf(m, sc[i][j]);
            float s = 0.f;
            for (int j = 0; j < NTOK; ++j) { float e = __expf(sc[i][j] - m); sc[i][j] = e; s += e; }
            float inv = 1.f / s;
            for (int j = 0; j < NTOK; ++j) sc[i][j] *= inv;
        }
        __syncthreads();
        // ---- out1[i, h*32+d] = sum_j p[i][j] * v[j][d] ----
        for (int idx = tid; idx < NTOK * HDIM; idx += 256) {
            int i = idx >> 5;
            int d = idx & 31;
            float acc = 0.f;
            for (int j = 0; j < NTOK; ++j) acc += sc[i][j] * vs[j][d];
            out1[((size_t)b * NTOK + i) * DIMC + h * HDIM + d] = acc;
        }
    }
}

// ---------------- launch ------------------------------------------------------
extern "C" void kernel_launch(void* const* d_in, const int* in_sizes, int n_in,
                              void* d_out, int out_size, void* d_ws, size_t ws_size,
                              hipStream_t stream) {
    const float* x          = (const float*)d_in[0];   // [2048,49,256]
    const float* mask       = (const float*)d_in[1];   // [64,49,49]
    const float* qkv_w      = (const float*)d_in[2];   // [256,768]
    const float* qkv_b      = (const float*)d_in[3];   // [768]
    const float* proj_w     = (const float*)d_in[4];   // [256,256]
    const float* proj_b     = (const float*)d_in[5];   // [256]
    const float* bias_table = (const float*)d_in[6];   // [169,8]
    const int*   rel_index  = (const int*)d_in[7];     // [49,49]
    float* out = (float*)d_out;

    const int B_TOTAL = 2048;
    const size_t BIASF_ELEMS = (size_t)NHEAD * NTOK * NTOK;          // 19208
    const size_t BIASF_BYTES = (BIASF_ELEMS * 4 + 255) & ~(size_t)255;
    const size_t PER_WIN_BYTES = (size_t)NTOK * (768 + 256) * 4;     // 200704

    // chunk size in windows (multiple of 64), sized to fit workspace
    size_t avail = (ws_size > BIASF_BYTES) ? (ws_size - BIASF_BYTES) : 0;
    int chunkW = (int)(avail / PER_WIN_BYTES);
    if (chunkW > B_TOTAL) chunkW = B_TOTAL;
    chunkW = (chunkW / 64) * 64;
    if (chunkW < 64) chunkW = 64;   // best effort

    float* biasf = (float*)d_ws;
    float* qkvbuf = (float*)((char*)d_ws + BIASF_BYTES);
    float* o1buf  = qkvbuf + (size_t)chunkW * NTOK * 768;

    bias_expand_kernel<<<(int)((BIASF_ELEMS + 255) / 256), 256, 0, stream>>>(
        bias_table, rel_index, biasf);

    for (int w0 = 0; w0 < B_TOTAL; w0 += chunkW) {
        int wc = B_TOTAL - w0; if (wc > chunkW) wc = chunkW;
        int Mc = wc * NTOK;

        dim3 g1(768 / 128, (Mc + 127) / 128);
        gemm_bias_kernel<<<g1, 256, 0, stream>>>(
            x + (size_t)w0 * NTOK * DIMC, qkv_w, qkv_b, qkvbuf, Mc, 768);

        attn_kernel<<<wc, 256, 0, stream>>>(qkvbuf, mask, biasf, o1buf, w0);

        dim3 g2(256 / 128, (Mc + 127) / 128);
        gemm_bias_kernel<<<g2, 256, 0, stream>>>(
            o1buf, proj_w, proj_b, out + (size_t)w0 * NTOK * DIMC, Mc, 256);
    }
}

// Round 2
// 465.481 us; speedup vs baseline: 2.6454x; 2.6454x over previous
//
#include <hip/hip_runtime.h>

#define NTOK 49
#define NHEAD 8
#define HDIM 32
#define DIMC 256
#define SCALE_F 0.17677669529663687f

typedef __attribute__((ext_vector_type(8))) short short8;
typedef __attribute__((ext_vector_type(4))) float f32x4;

#define AS1P(p) ((__attribute__((address_space(1))) void*)(p))
#define AS3P(p) ((__attribute__((address_space(3))) void*)(p))

__device__ inline unsigned short f2bf(float f) {
    unsigned int u = __float_as_uint(f);
    u += 0x7fffu + ((u >> 16) & 1u);
    return (unsigned short)(u >> 16);
}

// ---------------- fp32 -> bf16 bulk convert (8 elems/thread) ----------------
__global__ __launch_bounds__(256) void conv_bf16(const float* __restrict__ in,
    unsigned short* __restrict__ outp, int nv8)
{
    int i = blockIdx.x * 256 + threadIdx.x;
    if (i >= nv8) return;
    const float4* p = (const float4*)in + (size_t)i * 2;
    float4 a = p[0], b = p[1];
    union { unsigned short s[8]; uint4 v; } u;
    u.s[0] = f2bf(a.x); u.s[1] = f2bf(a.y); u.s[2] = f2bf(a.z); u.s[3] = f2bf(a.w);
    u.s[4] = f2bf(b.x); u.s[5] = f2bf(b.y); u.s[6] = f2bf(b.z); u.s[7] = f2bf(b.w);
    ((uint4*)outp)[i] = u.v;
}

// ---------------- pack W[K,N] fp32 -> Wp[K/8][N][8] bf16 --------------------
__global__ __launch_bounds__(256) void pack_w(const float* __restrict__ W,
    unsigned short* __restrict__ Wp, int K, int N)
{
    int idx = blockIdx.x * 256 + threadIdx.x;
    if (idx >= K * N) return;
    int k = idx / N, n = idx - k * N;
    Wp[((size_t)(k >> 3) * N + n) * 8 + (k & 7)] = f2bf(W[idx]);
}

// ---------------- bias+mask combined table bm[w][h][i][j] -------------------
__global__ __launch_bounds__(256) void bm_build(const float* __restrict__ bias_table,
    const int* __restrict__ rel_index, const float* __restrict__ mask,
    float* __restrict__ bm)
{
    int idx = blockIdx.x * 256 + threadIdx.x;
    if (idx >= 64 * NHEAD * NTOK * NTOK) return;
    int wh = idx / (NTOK * NTOK);
    int ij = idx - wh * (NTOK * NTOK);
    int w = wh >> 3, h = wh & 7;
    bm[idx] = bias_table[rel_index[ij] * NHEAD + h] + mask[(size_t)w * (NTOK * NTOK) + ij];
}

// ---------------- bf16 MFMA GEMM: Y[M,N] = A[M,256] @ W[256,N] + Bv ---------
// 128x128 tile, 4 waves, BK=32, global_load_lds staging. M % 128 == 0.
template <bool OUT_BF16>
__global__ __launch_bounds__(256) void gemm_mfma(
    const unsigned short* __restrict__ A,    // [M][256] bf16
    const unsigned short* __restrict__ Wp,   // [32][N][8] bf16 packed
    const float* __restrict__ Bv,            // [N]
    void* __restrict__ Yv,                   // [M][N]
    int N)
{
    __shared__ __align__(16) unsigned short As[4096];  // [4 kg][128 m][8 ki]
    __shared__ __align__(16) unsigned short Bs[4096];  // [4 kg][128 n][8 ki]

    const int tid  = threadIdx.x;
    const int lane = tid & 63;
    const int wv   = tid >> 6;
    const int quad = lane >> 4;
    const int l15  = lane & 15;
    const long m0  = (long)blockIdx.y * 128;
    const int  n0  = blockIdx.x * 128;
    const int  wm  = (wv >> 1) * 64;
    const int  wn  = (wv & 1) * 64;

    const unsigned short* ga0 = A + (size_t)(m0 + lane) * 256 + wv * 8;
    const unsigned short* ga1 = A + (size_t)(m0 + 64 + lane) * 256 + wv * 8;
    const unsigned short* gb0 = Wp + ((size_t)wv * N + n0 + lane) * 8;
    const unsigned short* gb1 = Wp + ((size_t)wv * N + n0 + 64 + lane) * 8;

    f32x4 acc[4][4];
    #pragma unroll
    for (int i = 0; i < 4; ++i)
        #pragma unroll
        for (int j = 0; j < 4; ++j) acc[i][j] = (f32x4){0.f, 0.f, 0.f, 0.f};

    for (int k0 = 0; k0 < 256; k0 += 32) {
        const size_t bofs = (size_t)(k0 >> 3) * N * 8;
        __builtin_amdgcn_global_load_lds(AS1P(ga0 + k0),   AS3P(As + wv * 1024),       16, 0, 0);
        __builtin_amdgcn_global_load_lds(AS1P(ga1 + k0),   AS3P(As + wv * 1024 + 512), 16, 0, 0);
        __builtin_amdgcn_global_load_lds(AS1P(gb0 + bofs), AS3P(Bs + wv * 1024),       16, 0, 0);
        __builtin_amdgcn_global_load_lds(AS1P(gb1 + bofs), AS3P(Bs + wv * 1024 + 512), 16, 0, 0);
        __syncthreads();
        short8 af[4], bq[4];
        #pragma unroll
        for (int t = 0; t < 4; ++t) {
            af[t] = *(const short8*)(As + quad * 1024 + (wm + t * 16 + l15) * 8);
            bq[t] = *(const short8*)(Bs + quad * 1024 + (wn + t * 16 + l15) * 8);
        }
        #pragma unroll
        for (int ti = 0; ti < 4; ++ti)
            #pragma unroll
            for (int tj = 0; tj < 4; ++tj)
                acc[ti][tj] = __builtin_amdgcn_mfma_f32_16x16x32_bf16(af[ti], bq[tj], acc[ti][tj], 0, 0, 0);
        __syncthreads();
    }

    #pragma unroll
    for (int ti = 0; ti < 4; ++ti) {
        #pragma unroll
        for (int r = 0; r < 4; ++r) {
            const long row = m0 + wm + ti * 16 + quad * 4 + r;
            #pragma unroll
            for (int tj = 0; tj < 4; ++tj) {
                const int col = n0 + wn + tj * 16 + l15;
                float v = acc[ti][tj][r] + Bv[col];
                if (OUT_BF16) ((unsigned short*)Yv)[row * N + col] = f2bf(v);
                else          ((float*)Yv)[row * N + col] = v;
            }
        }
    }
}

// ---------------- MFMA attention: 1 wave per (window, head) ------------------
// qkvb: [wc*49][768] bf16, col = s*256 + h*32 + d.  o1b: [wc*49][256] bf16.
__global__ __launch_bounds__(64) void attn_mfma(
    const unsigned short* __restrict__ qkvb,
    const float* __restrict__ bm,        // [64][8][49][49]
    unsigned short* __restrict__ o1b,
    int win0)
{
    __shared__ __align__(16) unsigned short Qs[2048];  // [4 kg][64 m][8 ki]
    __shared__ __align__(16) unsigned short Ks[2048];  // [4 kg][64 j][8 ki]
    __shared__ __align__(16) unsigned short Ps[4096];  // [8 kg][64 m][8 ki]
    __shared__ __align__(16) unsigned short Vt[2304];  // [32 d][72: 8 g * 8 ji + pad]

    const int lane = threadIdx.x;
    const int b    = blockIdx.x;
    const int h    = blockIdx.y;
    const int w    = (win0 + b) & 63;
    const int quad = lane >> 4;
    const int l15  = lane & 15;

    // ---- stage q,k,v (lane = token; zero rows >= 49) ----
    uint4 qw[4], kw[4], vw[4];
    const unsigned short* rp = qkvb + ((size_t)b * NTOK + lane) * 768 + h * HDIM;
    if (lane < NTOK) {
        #pragma unroll
        for (int c = 0; c < 4; ++c) {
            qw[c] = *(const uint4*)(rp + c * 8);
            kw[c] = *(const uint4*)(rp + 256 + c * 8);
            vw[c] = *(const uint4*)(rp + 512 + c * 8);
        }
    } else {
        #pragma unroll
        for (int c = 0; c < 4; ++c) {
            qw[c] = make_uint4(0u, 0u, 0u, 0u); kw[c] = qw[c]; vw[c] = qw[c];
        }
    }
    #pragma unroll
    for (int c = 0; c < 4; ++c) {
        *(uint4*)(Qs + c * 512 + lane * 8) = qw[c];
        *(uint4*)(Ks + c * 512 + lane * 8) = kw[c];
    }
    #pragma unroll
    for (int c = 0; c < 4; ++c) {
        unsigned int uu[4] = {vw[c].x, vw[c].y, vw[c].z, vw[c].w};
        #pragma unroll
        for (int e = 0; e < 4; ++e) {
            int d = c * 8 + e * 2;
            Vt[(size_t)d * 72 + lane]       = (unsigned short)(uu[e] & 0xffffu);
            Vt[(size_t)(d + 1) * 72 + lane] = (unsigned short)(uu[e] >> 16);
        }
    }
    __syncthreads();

    // ---- S = Q K^T (16 mfma, K=32) ----
    short8 aq[4], bk[4];
    #pragma unroll
    for (int t = 0; t < 4; ++t) {
        aq[t] = *(const short8*)(Qs + quad * 512 + (t * 16 + l15) * 8);
        bk[t] = *(const short8*)(Ks + quad * 512 + (t * 16 + l15) * 8);
    }
    f32x4 sa[4][4];
    #pragma unroll
    for (int ti = 0; ti < 4; ++ti)
        #pragma unroll
        for (int tj = 0; tj < 4; ++tj) {
            f32x4 z = (f32x4){0.f, 0.f, 0.f, 0.f};
            sa[ti][tj] = __builtin_amdgcn_mfma_f32_16x16x32_bf16(aq[ti], bk[tj], z, 0, 0, 0);
        }

    // ---- scale + bias + mask, softmax across row (16-lane shfl groups) ----
    const float* bmb = bm + (size_t)(w * NHEAD + h) * (NTOK * NTOK);
    float inv[4][4];
    #pragma unroll
    for (int ti = 0; ti < 4; ++ti) {
        #pragma unroll
        for (int r = 0; r < 4; ++r) {
            const int row = ti * 16 + quad * 4 + r;
            float sv[4];
            #pragma unroll
            for (int tj = 0; tj < 4; ++tj) {
                const int col = tj * 16 + l15;
                float s;
                if (col < NTOK) {
                    float add = (row < NTOK) ? bmb[row * NTOK + col] : 0.f;
                    s = sa[ti][tj][r] * SCALE_F + add;
                } else {
                    s = -__builtin_inff();
                }
                sv[tj] = s;
            }
            float mx = fmaxf(fmaxf(sv[0], sv[1]), fmaxf(sv[2], sv[3]));
            mx = fmaxf(mx, __shfl_xor(mx, 1, 16));
            mx = fmaxf(mx, __shfl_xor(mx, 2, 16));
            mx = fmaxf(mx, __shfl_xor(mx, 4, 16));
            mx = fmaxf(mx, __shfl_xor(mx, 8, 16));
            float e0 = __expf(sv[0] - mx), e1 = __expf(sv[1] - mx);
            float e2 = __expf(sv[2] - mx), e3 = __expf(sv[3] - mx);
            sa[ti][0][r] = e0; sa[ti][1][r] = e1; sa[ti][2][r] = e2; sa[ti][3][r] = e3;
            float sum = (e0 + e1) + (e2 + e3);
            sum += __shfl_xor(sum, 1, 16);
            sum += __shfl_xor(sum, 2, 16);
            sum += __shfl_xor(sum, 4, 16);
            sum += __shfl_xor(sum, 8, 16);
            inv[ti][r] = 1.f / sum;
        }
    }

    // ---- P (unnormalized e, bf16) -> LDS in A-operand layout ----
    #pragma unroll
    for (int ti = 0; ti < 4; ++ti)
        #pragma unroll
        for (int tj = 0; tj < 4; ++tj)
            #pragma unroll
            for (int r = 0; r < 4; ++r) {
                const int row = ti * 16 + quad * 4 + r;
                const int col = tj * 16 + l15;
                Ps[((col >> 3) * 64 + row) * 8 + (col & 7)] = f2bf(sa[ti][tj][r]);
            }
    __syncthreads();

    // ---- O = P V (K=64 via 2 chunks), then scale rows by 1/sum ----
    short8 pa[4][2], vb2[2][2];
    #pragma unroll
    for (int ti = 0; ti < 4; ++ti)
        #pragma unroll
        for (int kc = 0; kc < 2; ++kc)
            pa[ti][kc] = *(const short8*)(Ps + ((kc * 4 + quad) * 64 + ti * 16 + l15) * 8);
    #pragma unroll
    for (int td = 0; td < 2; ++td)
        #pragma unroll
        for (int kc = 0; kc < 2; ++kc)
            vb2[td][kc] = *(const short8*)(Vt + (size_t)(td * 16 + l15) * 72 + (kc * 4 + quad) * 8);
    f32x4 oa[4][2];
    #pragma unroll
    for (int ti = 0; ti < 4; ++ti)
        #pragma unroll
        for (int td = 0; td < 2; ++td) {
            f32x4 z = (f32x4){0.f, 0.f, 0.f, 0.f};
            z = __builtin_amdgcn_mfma_f32_16x16x32_bf16(pa[ti][0], vb2[td][0], z, 0, 0, 0);
            oa[ti][td] = __builtin_amdgcn_mfma_f32_16x16x32_bf16(pa[ti][1], vb2[td][1], z, 0, 0, 0);
        }

    #pragma unroll
    for (int ti = 0; ti < 4; ++ti)
        #pragma unroll
        for (int r = 0; r < 4; ++r) {
            const int row = ti * 16 + quad * 4 + r;
            if (row < NTOK) {
                const float si = inv[ti][r];
                unsigned short* op = o1b + ((size_t)b * NTOK + row) * DIMC + h * HDIM;
                #pragma unroll
                for (int td = 0; td < 2; ++td)
                    op[td * 16 + l15] = f2bf(oa[ti][td][r] * si);
            }
        }
}

// ---------------- launch ------------------------------------------------------
extern "C" void kernel_launch(void* const* d_in, const int* in_sizes, int n_in,
                              void* d_out, int out_size, void* d_ws, size_t ws_size,
                              hipStream_t stream)
{
    const float* x          = (const float*)d_in[0];
    const float* mask       = (const float*)d_in[1];
    const float* qkv_w      = (const float*)d_in[2];
    const float* qkv_b      = (const float*)d_in[3];
    const float* proj_w     = (const float*)d_in[4];
    const float* proj_b     = (const float*)d_in[5];
    const float* bias_table = (const float*)d_in[6];
    const int*   rel_index  = (const int*)d_in[7];
    float* outp = (float*)d_out;

    const int B_TOTAL = 2048;
    char* ws = (char*)d_ws;
    size_t off = 0;
    auto carve = [&](size_t bytes) -> void* {
        void* p = ws + off; off += (bytes + 255) & ~(size_t)255; return p;
    };
    unsigned short* WpQ = (unsigned short*)carve((size_t)256 * 768 * 2);
    unsigned short* WpP = (unsigned short*)carve((size_t)256 * 256 * 2);
    float* bm = (float*)carve((size_t)64 * NHEAD * NTOK * NTOK * 4);
    const size_t fixed = off;
    const size_t PER_WIN = (size_t)NTOK * 256 * 2 + (size_t)NTOK * 768 * 2 + (size_t)NTOK * 256 * 2;
    size_t avail = (ws_size > fixed + 1024) ? (ws_size - fixed - 1024) : 0;
    int chunkW = (int)(avail / PER_WIN);
    if (chunkW > B_TOTAL) chunkW = B_TOTAL;
    chunkW &= ~127;
    if (chunkW < 128) chunkW = 128;
    unsigned short* x_bf = (unsigned short*)carve((size_t)chunkW * NTOK * 256 * 2);
    unsigned short* qkvb = (unsigned short*)carve((size_t)chunkW * NTOK * 768 * 2);
    unsigned short* o1b  = (unsigned short*)carve((size_t)chunkW * NTOK * 256 * 2);

    pack_w<<<(256 * 768 + 255) / 256, 256, 0, stream>>>(qkv_w, WpQ, 256, 768);
    pack_w<<<(256 * 256 + 255) / 256, 256, 0, stream>>>(proj_w, WpP, 256, 256);
    bm_build<<<(64 * NHEAD * NTOK * NTOK + 255) / 256, 256, 0, stream>>>(
        bias_table, rel_index, mask, bm);

    for (int w0 = 0; w0 < B_TOTAL; w0 += chunkW) {
        int wc = B_TOTAL - w0; if (wc > chunkW) wc = chunkW;
        const int Mc = wc * NTOK;
        const int nv8 = Mc * 32;
        conv_bf16<<<(nv8 + 255) / 256, 256, 0, stream>>>(
            x + (size_t)w0 * NTOK * DIMC, x_bf, nv8);
        gemm_mfma<true ><<<dim3(6, Mc / 128), 256, 0, stream>>>(x_bf, WpQ, qkv_b, qkvb, 768);
        attn_mfma<<<dim3(wc, NHEAD), 64, 0, stream>>>(qkvb, bm, o1b, w0);
        gemm_mfma<false><<<dim3(2, Mc / 128), 256, 0, stream>>>(
            o1b, WpP, proj_b, outp + (size_t)w0 * NTOK * DIMC, 256);
    }
}

// Round 3
// 400.489 us; speedup vs baseline: 3.0747x; 1.1623x over previous
//
#include <hip/hip_runtime.h>

#define NTOK 49
#define NHEAD 8
#define HDIM 32
#define DIMC 256
#define SCALE_F 0.17677669529663687f

typedef __attribute__((ext_vector_type(8))) short short8;
typedef __attribute__((ext_vector_type(4))) float f32x4;

#define AS1P(p) ((__attribute__((address_space(1))) void*)(p))
#define AS3P(p) ((__attribute__((address_space(3))) void*)(p))

__device__ inline unsigned short f2bf(float f) {
    unsigned int u = __float_as_uint(f);
    u += 0x7fffu + ((u >> 16) & 1u);
    return (unsigned short)(u >> 16);
}

// ---------------- fp32 -> bf16 bulk convert (8 elems/thread) ----------------
__global__ __launch_bounds__(256) void conv_bf16(const float* __restrict__ in,
    unsigned short* __restrict__ outp, int nv8)
{
    int i = blockIdx.x * 256 + threadIdx.x;
    if (i >= nv8) return;
    const float4* p = (const float4*)in + (size_t)i * 2;
    float4 a = p[0], b = p[1];
    union { unsigned short s[8]; uint4 v; } u;
    u.s[0] = f2bf(a.x); u.s[1] = f2bf(a.y); u.s[2] = f2bf(a.z); u.s[3] = f2bf(a.w);
    u.s[4] = f2bf(b.x); u.s[5] = f2bf(b.y); u.s[6] = f2bf(b.z); u.s[7] = f2bf(b.w);
    ((uint4*)outp)[i] = u.v;
}

// ---------------- pack W[K,N] fp32 -> Wp[K/8][N][8] bf16 --------------------
__global__ __launch_bounds__(256) void pack_w(const float* __restrict__ W,
    unsigned short* __restrict__ Wp, int K, int N)
{
    int idx = blockIdx.x * 256 + threadIdx.x;
    if (idx >= K * N) return;
    int k = idx / N, n = idx - k * N;
    Wp[((size_t)(k >> 3) * N + n) * 8 + (k & 7)] = f2bf(W[idx]);
}

// ---------------- bias+mask combined table bm[w][h][i][j] -------------------
__global__ __launch_bounds__(256) void bm_build(const float* __restrict__ bias_table,
    const int* __restrict__ rel_index, const float* __restrict__ mask,
    float* __restrict__ bm)
{
    int idx = blockIdx.x * 256 + threadIdx.x;
    if (idx >= 64 * NHEAD * NTOK * NTOK) return;
    int wh = idx / (NTOK * NTOK);
    int ij = idx - wh * (NTOK * NTOK);
    int w = wh >> 3, h = wh & 7;
    bm[idx] = bias_table[rel_index[ij] * NHEAD + h] + mask[(size_t)w * (NTOK * NTOK) + ij];
}

// ---------------- bf16 MFMA GEMM: Y[M,N] = A[M,256] @ W[256,N] + Bv ---------
// 128x128 tile, 4 waves, BK=32, global_load_lds staging. M % 128 == 0.
template <bool OUT_BF16>
__global__ __launch_bounds__(256) void gemm_mfma(
    const unsigned short* __restrict__ A,    // [M][256] bf16
    const unsigned short* __restrict__ Wp,   // [32][N][8] bf16 packed
    const float* __restrict__ Bv,            // [N]
    void* __restrict__ Yv,                   // [M][N]
    int N)
{
    __shared__ __align__(16) unsigned short As[4096];  // [4 kg][128 m][8 ki]
    __shared__ __align__(16) unsigned short Bs[4096];  // [4 kg][128 n][8 ki]

    const int tid  = threadIdx.x;
    const int lane = tid & 63;
    const int wv   = tid >> 6;
    const int quad = lane >> 4;
    const int l15  = lane & 15;
    const long m0  = (long)blockIdx.y * 128;
    const int  n0  = blockIdx.x * 128;
    const int  wm  = (wv >> 1) * 64;
    const int  wn  = (wv & 1) * 64;

    const unsigned short* ga0 = A + (size_t)(m0 + lane) * 256 + wv * 8;
    const unsigned short* ga1 = A + (size_t)(m0 + 64 + lane) * 256 + wv * 8;
    const unsigned short* gb0 = Wp + ((size_t)wv * N + n0 + lane) * 8;
    const unsigned short* gb1 = Wp + ((size_t)wv * N + n0 + 64 + lane) * 8;

    f32x4 acc[4][4];
    #pragma unroll
    for (int i = 0; i < 4; ++i)
        #pragma unroll
        for (int j = 0; j < 4; ++j) acc[i][j] = (f32x4){0.f, 0.f, 0.f, 0.f};

    for (int k0 = 0; k0 < 256; k0 += 32) {
        const size_t bofs = (size_t)(k0 >> 3) * N * 8;
        __builtin_amdgcn_global_load_lds(AS1P(ga0 + k0),   AS3P(As + wv * 1024),       16, 0, 0);
        __builtin_amdgcn_global_load_lds(AS1P(ga1 + k0),   AS3P(As + wv * 1024 + 512), 16, 0, 0);
        __builtin_amdgcn_global_load_lds(AS1P(gb0 + bofs), AS3P(Bs + wv * 1024),       16, 0, 0);
        __builtin_amdgcn_global_load_lds(AS1P(gb1 + bofs), AS3P(Bs + wv * 1024 + 512), 16, 0, 0);
        __syncthreads();
        short8 af[4], bq[4];
        #pragma unroll
        for (int t = 0; t < 4; ++t) {
            af[t] = *(const short8*)(As + quad * 1024 + (wm + t * 16 + l15) * 8);
            bq[t] = *(const short8*)(Bs + quad * 1024 + (wn + t * 16 + l15) * 8);
        }
        #pragma unroll
        for (int ti = 0; ti < 4; ++ti)
            #pragma unroll
            for (int tj = 0; tj < 4; ++tj)
                acc[ti][tj] = __builtin_amdgcn_mfma_f32_16x16x32_bf16(af[ti], bq[tj], acc[ti][tj], 0, 0, 0);
        __syncthreads();
    }

    #pragma unroll
    for (int ti = 0; ti < 4; ++ti) {
        #pragma unroll
        for (int r = 0; r < 4; ++r) {
            const long row = m0 + wm + ti * 16 + quad * 4 + r;
            #pragma unroll
            for (int tj = 0; tj < 4; ++tj) {
                const int col = n0 + wn + tj * 16 + l15;
                float v = acc[ti][tj][r] + Bv[col];
                if (OUT_BF16) ((unsigned short*)Yv)[row * N + col] = f2bf(v);
                else          ((float*)Yv)[row * N + col] = v;
            }
        }
    }
}

// ---------------- MFMA attention v2: 2 waves/block, direct Q/K frag loads ----
// qkvb: [wc*49][768] bf16, col = s*256 + h*32 + d.  o1b: [wc*49][256] bf16.
// LDS per wave: 3528 shorts (7056B), V-transpose aliased under P (disjoint in time).
__global__ __launch_bounds__(128) void attn_mfma(
    const unsigned short* __restrict__ qkvb,
    const float* __restrict__ bm,        // [64][8][49][49]
    unsigned short* __restrict__ o1b,
    int win0)
{
    __shared__ __align__(16) unsigned short SMEM[2 * 3528];

    const int wvid = threadIdx.x >> 6;
    const int lane = threadIdx.x & 63;
    const int h    = blockIdx.x * 2 + wvid;     // head
    const int b    = blockIdx.y;                // local window
    const int w    = (win0 + b) & 63;
    const int quad = lane >> 4;
    const int l15  = lane & 15;

    unsigned short* Vt = SMEM + wvid * 3528;   // [32 d][72] (2304 shorts), phase 1
    unsigned short* Ps = SMEM + wvid * 3528;   // [49 row][72] (3528 shorts), phase 2

    const unsigned short* wbase = qkvb + (size_t)b * NTOK * 768 + h * HDIM;

    // ---- stage V^T: lane = token (clamped), 32 scalar b16 writes ----
    {
        const int tok = (lane < NTOK) ? lane : (NTOK - 1);
        const unsigned short* vp = wbase + (size_t)tok * 768 + 512;
        #pragma unroll
        for (int c = 0; c < 4; ++c) {
            uint4 vv = *(const uint4*)(vp + c * 8);
            unsigned int uu[4] = {vv.x, vv.y, vv.z, vv.w};
            #pragma unroll
            for (int e = 0; e < 4; ++e) {
                int d = c * 8 + e * 2;
                Vt[d * 72 + lane]       = (unsigned short)(uu[e] & 0xffffu);
                Vt[(d + 1) * 72 + lane] = (unsigned short)(uu[e] >> 16);
            }
        }
    }

    // ---- Q/K fragments direct from global (16B contiguous per lane) ----
    short8 aq[4], bk[4];
    #pragma unroll
    for (int t = 0; t < 4; ++t) {
        int row = t * 16 + l15; if (row >= NTOK) row = NTOK - 1;
        const unsigned short* rp = wbase + (size_t)row * 768 + quad * 8;
        aq[t] = *(const short8*)(rp);
        bk[t] = *(const short8*)(rp + 256);
    }

    // ---- S = Q K^T (16 mfma, K=32) ----
    f32x4 sa[4][4];
    #pragma unroll
    for (int ti = 0; ti < 4; ++ti)
        #pragma unroll
        for (int tj = 0; tj < 4; ++tj) {
            f32x4 z = (f32x4){0.f, 0.f, 0.f, 0.f};
            sa[ti][tj] = __builtin_amdgcn_mfma_f32_16x16x32_bf16(aq[ti], bk[tj], z, 0, 0, 0);
        }

    // ---- read V fragments BEFORE P overwrites the aliased LDS ----
    short8 vb2[2][2];
    #pragma unroll
    for (int td = 0; td < 2; ++td)
        #pragma unroll
        for (int kc = 0; kc < 2; ++kc)
            vb2[td][kc] = *(const short8*)(Vt + (td * 16 + l15) * 72 + kc * 32 + quad * 8);

    // ---- scale + bias + mask, softmax across row (16-lane shfl groups) ----
    const float* bmb = bm + (size_t)(w * NHEAD + h) * (NTOK * NTOK);
    float inv[4][4];
    #pragma unroll
    for (int ti = 0; ti < 4; ++ti) {
        #pragma unroll
        for (int r = 0; r < 4; ++r) {
            const int row = ti * 16 + quad * 4 + r;
            float sv[4];
            #pragma unroll
            for (int tj = 0; tj < 4; ++tj) {
                const int col = tj * 16 + l15;
                float s;
                if (col < NTOK) {
                    float add = (row < NTOK) ? bmb[row * NTOK + col] : 0.f;
                    s = sa[ti][tj][r] * SCALE_F + add;
                } else {
                    s = -__builtin_inff();
                }
                sv[tj] = s;
            }
            float mx = fmaxf(fmaxf(sv[0], sv[1]), fmaxf(sv[2], sv[3]));
            mx = fmaxf(mx, __shfl_xor(mx, 1, 16));
            mx = fmaxf(mx, __shfl_xor(mx, 2, 16));
            mx = fmaxf(mx, __shfl_xor(mx, 4, 16));
            mx = fmaxf(mx, __shfl_xor(mx, 8, 16));
            float e0 = __expf(sv[0] - mx), e1 = __expf(sv[1] - mx);
            float e2 = __expf(sv[2] - mx), e3 = __expf(sv[3] - mx);
            sa[ti][0][r] = e0; sa[ti][1][r] = e1; sa[ti][2][r] = e2; sa[ti][3][r] = e3;
            float sum = (e0 + e1) + (e2 + e3);
            sum += __shfl_xor(sum, 1, 16);
            sum += __shfl_xor(sum, 2, 16);
            sum += __shfl_xor(sum, 4, 16);
            sum += __shfl_xor(sum, 8, 16);
            inv[ti][r] = 1.f / sum;
        }
    }

    // ---- make sure both waves' V-fragment reads retired before P overwrite ----
    __syncthreads();

    // ---- P (unnormalized e, bf16) -> LDS row-major [49][72] ----
    #pragma unroll
    for (int ti = 0; ti < 4; ++ti)
        #pragma unroll
        for (int r = 0; r < 4; ++r) {
            const int row = ti * 16 + quad * 4 + r;
            if (row < NTOK) {
                #pragma unroll
                for (int tj = 0; tj < 4; ++tj)
                    Ps[row * 72 + tj * 16 + l15] = f2bf(sa[ti][tj][r]);
            }
        }

    // ---- O = P V (K=64 via 2 chunks), rows clamped (rows>=49 unused) ----
    short8 pa[4][2];
    #pragma unroll
    for (int ti = 0; ti < 4; ++ti) {
        int row = ti * 16 + l15; if (row >= NTOK) row = NTOK - 1;
        #pragma unroll
        for (int kc = 0; kc < 2; ++kc)
            pa[ti][kc] = *(const short8*)(Ps + row * 72 + kc * 32 + quad * 8);
    }
    f32x4 oa[4][2];
    #pragma unroll
    for (int ti = 0; ti < 4; ++ti)
        #pragma unroll
        for (int td = 0; td < 2; ++td) {
            f32x4 z = (f32x4){0.f, 0.f, 0.f, 0.f};
            z = __builtin_amdgcn_mfma_f32_16x16x32_bf16(pa[ti][0], vb2[td][0], z, 0, 0, 0);
            oa[ti][td] = __builtin_amdgcn_mfma_f32_16x16x32_bf16(pa[ti][1], vb2[td][1], z, 0, 0, 0);
        }

    #pragma unroll
    for (int ti = 0; ti < 4; ++ti)
        #pragma unroll
        for (int r = 0; r < 4; ++r) {
            const int row = ti * 16 + quad * 4 + r;
            if (row < NTOK) {
                const float si = inv[ti][r];
                unsigned short* op = o1b + ((size_t)b * NTOK + row) * DIMC + h * HDIM;
                #pragma unroll
                for (int td = 0; td < 2; ++td)
                    op[td * 16 + l15] = f2bf(oa[ti][td][r] * si);
            }
        }
}

// ---------------- launch ------------------------------------------------------
extern "C" void kernel_launch(void* const* d_in, const int* in_sizes, int n_in,
                              void* d_out, int out_size, void* d_ws, size_t ws_size,
                              hipStream_t stream)
{
    const float* x          = (const float*)d_in[0];
    const float* mask       = (const float*)d_in[1];
    const float* qkv_w      = (const float*)d_in[2];
    const float* qkv_b      = (const float*)d_in[3];
    const float* proj_w     = (const float*)d_in[4];
    const float* proj_b     = (const float*)d_in[5];
    const float* bias_table = (const float*)d_in[6];
    const int*   rel_index  = (const int*)d_in[7];
    float* outp = (float*)d_out;

    const int B_TOTAL = 2048;
    char* ws = (char*)d_ws;
    size_t off = 0;
    auto carve = [&](size_t bytes) -> void* {
        void* p = ws + off; off += (bytes + 255) & ~(size_t)255; return p;
    };
    unsigned short* WpQ = (unsigned short*)carve((size_t)256 * 768 * 2);
    unsigned short* WpP = (unsigned short*)carve((size_t)256 * 256 * 2);
    float* bm = (float*)carve((size_t)64 * NHEAD * NTOK * NTOK * 4);
    const size_t fixed = off;
    const size_t PER_WIN = (size_t)NTOK * 256 * 2 + (size_t)NTOK * 768 * 2 + (size_t)NTOK * 256 * 2;
    size_t avail = (ws_size > fixed + 1024) ? (ws_size - fixed - 1024) : 0;
    int chunkW = (int)(avail / PER_WIN);
    if (chunkW > B_TOTAL) chunkW = B_TOTAL;
    chunkW &= ~127;
    if (chunkW < 128) chunkW = 128;
    unsigned short* x_bf = (unsigned short*)carve((size_t)chunkW * NTOK * 256 * 2);
    unsigned short* qkvb = (unsigned short*)carve((size_t)chunkW * NTOK * 768 * 2);
    unsigned short* o1b  = (unsigned short*)carve((size_t)chunkW * NTOK * 256 * 2);

    pack_w<<<(256 * 768 + 255) / 256, 256, 0, stream>>>(qkv_w, WpQ, 256, 768);
    pack_w<<<(256 * 256 + 255) / 256, 256, 0, stream>>>(proj_w, WpP, 256, 256);
    bm_build<<<(64 * NHEAD * NTOK * NTOK + 255) / 256, 256, 0, stream>>>(
        bias_table, rel_index, mask, bm);

    for (int w0 = 0; w0 < B_TOTAL; w0 += chunkW) {
        int wc = B_TOTAL - w0; if (wc > chunkW) wc = chunkW;
        const int Mc = wc * NTOK;
        const int nv8 = Mc * 32;
        conv_bf16<<<(nv8 + 255) / 256, 256, 0, stream>>>(
            x + (size_t)w0 * NTOK * DIMC, x_bf, nv8);
        gemm_mfma<true ><<<dim3(6, Mc / 128), 256, 0, stream>>>(x_bf, WpQ, qkv_b, qkvb, 768);
        attn_mfma<<<dim3(NHEAD / 2, wc), 128, 0, stream>>>(qkvb, bm, o1b, w0);
        gemm_mfma<false><<<dim3(2, Mc / 128), 256, 0, stream>>>(
            o1b, WpP, proj_b, outp + (size_t)w0 * NTOK * DIMC, 256);
    }
}